// Round 5
// baseline (1832.847 us; speedup 1.0000x reference)
//
#include <hip/hip_runtime.h>
#include <hip/hip_bf16.h>
#include <math.h>

// Problem constants
// B=32, T=12, N=2048, C=1, D=10, K=2, H=32
// CH = C+H = 33, COLS = B*CH = 1056, padded to COLP = 1152 (=9*128)

#define NNODE 2048
#define NB 32
#define NT 12
#define NH 32
#define CH 33
#define COLS 1056
#define COLP 1152
#define ND 10
#define KPAD 96    // gconv K = 2*33 = 66, zero-padded to 3 MFMA k-tiles
#define GPAD 104   // LDS row stride (halfs) for cat tiles: 16B-aligned, 2-way banks

// A is stored fp16 pre-scaled by ASCALE (power of 2, exact) to keep softmax
// tail entries out of fp16-denormal range; mm epilogue multiplies by 1/ASCALE.
#define ASCALE 256.0f
#define AINV 0.00390625f

// split-K factor for mm: 2048 = 4 * 512 -> grid 9*16*4 = 576 blocks
#define KSPLIT 4
#define KCHUNK 512
#define YSTRIDEH ((size_t)NNODE * COLP)  // one fp16 Y partial, in halfs

typedef _Float16 half8 __attribute__((ext_vector_type(8)));
typedef float floatx4 __attribute__((ext_vector_type(4)));

// ---------------- workspace layout (in float slots) ----------------
constexpr size_t OFF_AH  = 0;                           // Ah fp16 2048*2048 -> 2,097,152 slots
constexpr size_t OFF_WGT = OFF_AH + 2097152u;           // Wgt fp16 [n][64][96] -> 6,291,456 slots
constexpr size_t OFF_WUT = OFF_WGT + 6291456u;          // Wut fp16 [n][32][96] -> 3,145,728 slots
constexpr size_t OFF_BG  = OFF_WUT + 3145728u;          // bg fp32 2048*64
constexpr size_t OFF_BU  = OFF_BG + 131072u;            // bu fp32 2048*32
constexpr size_t OFF_XS  = OFF_BU + 65536u;             // Xs fp16 2048*1152 -> 1,179,648 slots
constexpr size_t OFF_XS2 = OFF_XS + 1179648u;           // Xs2 fp16 -> 1,179,648 slots
constexpr size_t OFF_HS  = OFF_XS2 + 1179648u;          // Hs fp32 2048*32*32 = 2,097,152
constexpr size_t OFF_Y   = OFF_HS + 2097152u;           // Y fp16 4 partials -> 4,718,592 slots
constexpr size_t OFF_R   = OFF_Y + 4718592u;            // rbuf fp16 2048*1024 -> 1,048,576 slots
// end = 21,954,560 floats = ~87.8 MB

// ---------------- A = softmax(relu(E E^T), axis=1) * ASCALE, stored fp16 ----------------
__global__ __launch_bounds__(256) void adj_kernel(const float* __restrict__ E,
                                                  _Float16* __restrict__ Ah) {
    __shared__ float En[ND];
    __shared__ float red[256];
    const int n = blockIdx.x;
    const int t = threadIdx.x;
    if (t < ND) En[t] = E[n * ND + t];
    __syncthreads();
    float v[8];
    float mx = 0.f;
#pragma unroll
    for (int i = 0; i < 8; ++i) {
        const int m = t + i * 256;
        float acc = 0.f;
#pragma unroll
        for (int d = 0; d < ND; ++d) acc += En[d] * E[m * ND + d];
        acc = fmaxf(acc, 0.f);
        v[i] = acc;
        mx = fmaxf(mx, acc);
    }
    red[t] = mx;
    __syncthreads();
    for (int s = 128; s > 0; s >>= 1) {
        if (t < s) red[t] = fmaxf(red[t], red[t + s]);
        __syncthreads();
    }
    mx = red[0];
    __syncthreads();
    float sum = 0.f;
#pragma unroll
    for (int i = 0; i < 8; ++i) {
        v[i] = expf(v[i] - mx);
        sum += v[i];
    }
    red[t] = sum;
    __syncthreads();
    for (int s = 128; s > 0; s >>= 1) {
        if (t < s) red[t] += red[t + s];
        __syncthreads();
    }
    const float inv = ASCALE / red[0];
#pragma unroll
    for (int i = 0; i < 8; ++i)
        Ah[(size_t)n * NNODE + t + i * 256] = (_Float16)(v[i] * inv);
}

// ---------------- per-node weights, transposed to [n][o][k], k zero-padded to 96 ----------------
__global__ __launch_bounds__(256) void wg_kernel(const float* __restrict__ E,
                                                 const float* __restrict__ gW,
                                                 _Float16* __restrict__ Wgt) {
    const int idx = blockIdx.x * 256 + threadIdx.x;  // over 2048*64*96
    const int n = idx / 6144, rem = idx % 6144, o = rem / KPAD, k = rem % KPAD;
    float acc = 0.f;
    if (k < 66) {
        const int kk = (k >= 33) ? 1 : 0;
        const int i = k - 33 * kk;
        const float* g = gW + kk * 2112 + i * 64 + o;
#pragma unroll
        for (int d = 0; d < ND; ++d) acc += E[n * ND + d] * g[d * 4224];
    }
    Wgt[idx] = (_Float16)acc;
}

__global__ __launch_bounds__(256) void wu_kernel(const float* __restrict__ E,
                                                 const float* __restrict__ uW,
                                                 _Float16* __restrict__ Wut) {
    const int idx = blockIdx.x * 256 + threadIdx.x;  // over 2048*32*96
    const int n = idx / 3072, rem = idx % 3072, o = rem / KPAD, k = rem % KPAD;
    float acc = 0.f;
    if (k < 66) {
        const int kk = (k >= 33) ? 1 : 0;
        const int i = k - 33 * kk;
        const float* g = uW + kk * 1056 + i * 32 + o;
#pragma unroll
        for (int d = 0; d < ND; ++d) acc += E[n * ND + d] * g[d * 2112];
    }
    Wut[idx] = (_Float16)acc;
}

__global__ __launch_bounds__(256) void bias_kernel(const float* __restrict__ E,
                                                   const float* __restrict__ gb,
                                                   const float* __restrict__ ub,
                                                   float* __restrict__ bg,
                                                   float* __restrict__ bu) {
    const int idx = blockIdx.x * 256 + threadIdx.x;
    if (idx < NNODE * 64) {
        const int n = idx >> 6, o = idx & 63;
        float acc = 0.f;
#pragma unroll
        for (int d = 0; d < ND; ++d) acc += E[n * ND + d] * gb[d * 64 + o];
        bg[idx] = acc;
    } else if (idx < NNODE * 64 + NNODE * 32) {
        const int j = idx - NNODE * 64;
        const int n = j >> 5, o = j & 31;
        float acc = 0.f;
#pragma unroll
        for (int d = 0; d < ND; ++d) acc += E[n * ND + d] * ub[d * 32 + o];
        bu[j] = acc;
    }
}

// ---------------- init: Xs = [x_0,0..], Xs2 = 0, Hs = 0 ----------------
__global__ __launch_bounds__(256) void setup_kernel(const float* __restrict__ src,
                                                    _Float16* __restrict__ Xs,
                                                    _Float16* __restrict__ Xs2,
                                                    float* __restrict__ Hs) {
    const int idx = blockIdx.x * 256 + threadIdx.x;
    if (idx >= NNODE * COLP) return;
    const int n = idx / COLP, c = idx % COLP;
    _Float16 v = (_Float16)0.f;
    if (c < COLS && (c % CH) == 0) {
        const int b = c / CH;
        v = (_Float16)src[(size_t)b * NT * NNODE + n];  // t = 0
    }
    Xs[idx] = v;
    Xs2[idx] = (_Float16)0.f;
    if (idx < NNODE * 1024) Hs[idx] = 0.f;
}

// ---------------- Y_part[z] = (A*ASCALE)[:,zK:..] @ X[zK:..,:] * (1/ASCALE), fp16 out ----------------
__global__ __launch_bounds__(256) void mm_kernel(const _Float16* __restrict__ Ah,
                                                 const _Float16* __restrict__ X,
                                                 _Float16* __restrict__ Y) {
    __shared__ unsigned short As[128][40];  // [m][k]
    __shared__ unsigned short Bs[128][40];  // [col][k] (transposed X tile)
    const int t = threadIdx.x;
    const int m0 = blockIdx.y * 128;
    const int c0 = blockIdx.x * 128;
    const int kz = blockIdx.z;
    _Float16* __restrict__ Yp = Y + (size_t)kz * YSTRIDEH;
    const int lane = t & 63;
    const int w = t >> 6;
    const int wm = (w & 1) * 64;
    const int wn = (w >> 1) * 64;
    const int lm = lane & 15;
    const int q = lane >> 4;

    // A staging: thread -> (row ar, 16-half chunk ac)
    const int ar = t >> 1;
    const int ac = (t & 1) * 16;
    // B staging: thread -> (col group cg: 8 cols, k-pair kp)
    const int cg = t & 15;
    const int kp = t >> 4;

    floatx4 acc[4][4] = {};

    const int kend = kz * KCHUNK + KCHUNK;
    for (int kt = kz * KCHUNK; kt < kend; kt += 32) {
        const unsigned short* pa =
            (const unsigned short*)Ah + (size_t)(m0 + ar) * NNODE + kt + ac;
        uint4 a0 = *(const uint4*)pa;
        uint4 a1 = *(const uint4*)(pa + 8);
        uint4 x0 = *(const uint4*)(X + (size_t)(kt + 2 * kp) * COLP + c0 + cg * 8);
        uint4 x1 = *(const uint4*)(X + (size_t)(kt + 2 * kp + 1) * COLP + c0 + cg * 8);
        *(uint4*)&As[ar][ac] = a0;
        *(uint4*)&As[ar][ac + 8] = a1;
        const unsigned short* p0 = (const unsigned short*)&x0;
        const unsigned short* p1 = (const unsigned short*)&x1;
#pragma unroll
        for (int j = 0; j < 8; ++j)
            *(unsigned*)&Bs[cg * 8 + j][2 * kp] =
                (unsigned)p0[j] | ((unsigned)p1[j] << 16);
        __syncthreads();
        half8 af[4], bf[4];
#pragma unroll
        for (int mt = 0; mt < 4; ++mt)
            af[mt] = *(const half8*)&As[wm + mt * 16 + lm][q * 8];
#pragma unroll
        for (int nt = 0; nt < 4; ++nt)
            bf[nt] = *(const half8*)&Bs[wn + nt * 16 + lm][q * 8];
#pragma unroll
        for (int mt = 0; mt < 4; ++mt)
#pragma unroll
            for (int nt = 0; nt < 4; ++nt)
                acc[mt][nt] = __builtin_amdgcn_mfma_f32_16x16x32_f16(
                    af[mt], bf[nt], acc[mt][nt], 0, 0, 0);
        __syncthreads();
    }
#pragma unroll
    for (int mt = 0; mt < 4; ++mt) {
#pragma unroll
        for (int nt = 0; nt < 4; ++nt) {
            const int row = m0 + wm + mt * 16 + q * 4;
            const int col = c0 + wn + nt * 16 + lm;
#pragma unroll
            for (int r = 0; r < 4; ++r)
                Yp[(size_t)(row + r) * COLP + col] = (_Float16)(acc[mt][nt][r] * AINV);
        }
    }
}

// ---------------- gate: MFMA per-node weight apply; writes Xs2 (fp16) + rbuf ----------------
// 4 nodes/block, 1 wave/node. cat[b][k] in LDS (k: 0..32 = x|h, 33..65 = y, 66..95 = 0).
// W fragments straight from global Wgt [n][o][96].
__global__ __launch_bounds__(256) void gate_kernel(const _Float16* __restrict__ Xs,
                                                   const _Float16* __restrict__ Y,
                                                   const _Float16* __restrict__ Wgt,
                                                   const float* __restrict__ bg,
                                                   const float* __restrict__ Hs,
                                                   _Float16* __restrict__ Xs2,
                                                   _Float16* __restrict__ rbuf) {
    __shared__ _Float16 catL[4][32][GPAD];
    const int t = threadIdx.x;
    const int n0 = blockIdx.x * 4;
    // cat staging: 2 threads per (node, b)
    {
        const int pair = t >> 1, which = t & 1;
        const int nd = pair >> 5, b = pair & 31;
        const size_t nrow = (size_t)(n0 + nd) * COLP + b * CH;
        if (which == 0) {
#pragma unroll
            for (int i = 0; i < CH; ++i) catL[nd][b][i] = Xs[nrow + i];
#pragma unroll
            for (int i = 66; i < KPAD; i += 2) *(unsigned*)&catL[nd][b][i] = 0u;
        } else {
#pragma unroll
            for (int i = 0; i < CH; ++i) {
                const float s = (float)Y[nrow + i] + (float)Y[YSTRIDEH + nrow + i] +
                                (float)Y[2 * YSTRIDEH + nrow + i] +
                                (float)Y[3 * YSTRIDEH + nrow + i];
                catL[nd][b][CH + i] = (_Float16)s;
            }
        }
    }
    __syncthreads();
    const int w = t >> 6, lane = t & 63, lm = lane & 15, q = lane >> 4;
    const int n = n0 + w;
    const _Float16* Wn = Wgt + (size_t)n * 6144;
    floatx4 acc[2][4] = {};
#pragma unroll
    for (int kt = 0; kt < 3; ++kt) {
        half8 af[2], bf[4];
#pragma unroll
        for (int mt = 0; mt < 2; ++mt)
            af[mt] = *(const half8*)&catL[w][mt * 16 + lm][kt * 32 + q * 8];
#pragma unroll
        for (int nt = 0; nt < 4; ++nt)
            bf[nt] = *(const half8*)(Wn + (nt * 16 + lm) * KPAD + kt * 32 + q * 8);
#pragma unroll
        for (int mt = 0; mt < 2; ++mt)
#pragma unroll
            for (int nt = 0; nt < 4; ++nt)
                acc[mt][nt] = __builtin_amdgcn_mfma_f32_16x16x32_f16(
                    af[mt], bf[nt], acc[mt][nt], 0, 0, 0);
    }
#pragma unroll
    for (int nt = 0; nt < 4; ++nt) {
        const int o = nt * 16 + lm;
        const float bias = bg[n * 64 + o];
#pragma unroll
        for (int mt = 0; mt < 2; ++mt) {
#pragma unroll
            for (int r = 0; r < 4; ++r) {
                const int b = mt * 16 + q * 4 + r;
                const float s = 1.f / (1.f + expf(-(acc[mt][nt][r] + bias)));
                if (o < 32) {
                    const float hold = Hs[(size_t)n * 1024 + b * 32 + o];
                    Xs2[(size_t)n * COLP + b * CH + 1 + o] = (_Float16)(s * hold);
                    if (o == 0)
                        Xs2[(size_t)n * COLP + b * CH] = catL[w][b][0];
                } else {
                    rbuf[(size_t)n * 1024 + b * 32 + (o - 32)] = (_Float16)s;
                }
            }
        }
    }
}

// ---------------- update: MFMA weight apply; writes Hs (fp32) + Xs (fp16) ----------------
__global__ __launch_bounds__(256) void upd_kernel(const _Float16* __restrict__ Xs2,
                                                  const _Float16* __restrict__ Y,
                                                  const _Float16* __restrict__ Wut,
                                                  const float* __restrict__ bu,
                                                  const _Float16* __restrict__ rbuf,
                                                  const float* __restrict__ src,
                                                  float* __restrict__ Hs,
                                                  _Float16* __restrict__ Xs, int tnext) {
    __shared__ _Float16 catL[4][32][GPAD];
    const int t = threadIdx.x;
    const int n0 = blockIdx.x * 4;
    {
        const int pair = t >> 1, which = t & 1;
        const int nd = pair >> 5, b = pair & 31;
        const size_t nrow = (size_t)(n0 + nd) * COLP + b * CH;
        if (which == 0) {
#pragma unroll
            for (int i = 0; i < CH; ++i) catL[nd][b][i] = Xs2[nrow + i];
#pragma unroll
            for (int i = 66; i < KPAD; i += 2) *(unsigned*)&catL[nd][b][i] = 0u;
        } else {
#pragma unroll
            for (int i = 0; i < CH; ++i) {
                const float s = (float)Y[nrow + i] + (float)Y[YSTRIDEH + nrow + i] +
                                (float)Y[2 * YSTRIDEH + nrow + i] +
                                (float)Y[3 * YSTRIDEH + nrow + i];
                catL[nd][b][CH + i] = (_Float16)s;
            }
        }
    }
    __syncthreads();
    const int w = t >> 6, lane = t & 63, lm = lane & 15, q = lane >> 4;
    const int n = n0 + w;
    const _Float16* Wn = Wut + (size_t)n * 3072;
    floatx4 acc[2][2] = {};
#pragma unroll
    for (int kt = 0; kt < 3; ++kt) {
        half8 af[2], bf[2];
#pragma unroll
        for (int mt = 0; mt < 2; ++mt)
            af[mt] = *(const half8*)&catL[w][mt * 16 + lm][kt * 32 + q * 8];
#pragma unroll
        for (int nt = 0; nt < 2; ++nt)
            bf[nt] = *(const half8*)(Wn + (nt * 16 + lm) * KPAD + kt * 32 + q * 8);
#pragma unroll
        for (int mt = 0; mt < 2; ++mt)
#pragma unroll
            for (int nt = 0; nt < 2; ++nt)
                acc[mt][nt] = __builtin_amdgcn_mfma_f32_16x16x32_f16(
                    af[mt], bf[nt], acc[mt][nt], 0, 0, 0);
    }
#pragma unroll
    for (int nt = 0; nt < 2; ++nt) {
        const int o = nt * 16 + lm;
        const float bias = bu[n * 32 + o];
#pragma unroll
        for (int mt = 0; mt < 2; ++mt) {
#pragma unroll
            for (int r = 0; r < 4; ++r) {
                const int b = mt * 16 + q * 4 + r;
                const float hc = tanhf(acc[mt][nt][r] + bias);
                const float rr = (float)rbuf[(size_t)n * 1024 + b * 32 + o];
                const size_t hidx = (size_t)n * 1024 + b * 32 + o;
                const float hnew = rr * Hs[hidx] + (1.f - rr) * hc;
                Hs[hidx] = hnew;
                Xs[(size_t)n * COLP + b * CH + 1 + o] = (_Float16)hnew;
                if (o == 0 && tnext < NT)
                    Xs[(size_t)n * COLP + b * CH] =
                        (_Float16)src[(size_t)b * NT * NNODE + (size_t)tnext * NNODE + n];
            }
        }
    }
}

// ---------------- out[b,0,n,t] = dot(h[b,n,:], convW[t,:]) + convb[t] ----------------
__global__ __launch_bounds__(256) void out_kernel(const float* __restrict__ Hs,
                                                  const float* __restrict__ cw,
                                                  const float* __restrict__ cb,
                                                  float* __restrict__ out) {
    __shared__ float h[NB * NH];
    __shared__ float cws[NT * NH];
    __shared__ float cbs[NT];
    const int n = blockIdx.x;
    const int t = threadIdx.x;
    for (int i = t; i < NT * NH; i += 256) cws[i] = cw[i];
    if (t < NT) cbs[t] = cb[t];
    for (int i = t; i < NB * NH; i += 256) h[i] = Hs[(size_t)n * 1024 + i];
    __syncthreads();
    for (int p = t; p < NB * NT; p += 256) {
        const int b = p / NT, tt = p % NT;
        float acc = cbs[tt];
#pragma unroll
        for (int j = 0; j < NH; ++j) acc += h[b * NH + j] * cws[tt * NH + j];
        out[(size_t)b * NNODE * NT + (size_t)n * NT + tt] = acc;
    }
}

extern "C" void kernel_launch(void* const* d_in, const int* in_sizes, int n_in,
                              void* d_out, int out_size, void* d_ws, size_t ws_size,
                              hipStream_t stream) {
    const float* src  = (const float*)d_in[0];
    const float* E    = (const float*)d_in[1];
    const float* gW   = (const float*)d_in[2];
    const float* gb   = (const float*)d_in[3];
    const float* uW   = (const float*)d_in[4];
    const float* ub   = (const float*)d_in[5];
    const float* cw   = (const float*)d_in[6];
    const float* cb   = (const float*)d_in[7];
    float* out = (float*)d_out;

    float* ws = (float*)d_ws;
    _Float16* Ah  = (_Float16*)(ws + OFF_AH);
    _Float16* Wgt = (_Float16*)(ws + OFF_WGT);
    _Float16* Wut = (_Float16*)(ws + OFF_WUT);
    float* bg  = ws + OFF_BG;
    float* bu  = ws + OFF_BU;
    _Float16* Xs  = (_Float16*)(ws + OFF_XS);
    _Float16* Xs2 = (_Float16*)(ws + OFF_XS2);
    float* Hs  = ws + OFF_HS;
    _Float16* Y   = (_Float16*)(ws + OFF_Y);
    _Float16* rb  = (_Float16*)(ws + OFF_R);

    adj_kernel<<<NNODE, 256, 0, stream>>>(E, Ah);
    wg_kernel<<<NNODE * 64 * KPAD / 256, 256, 0, stream>>>(E, gW, Wgt);
    wu_kernel<<<NNODE * 32 * KPAD / 256, 256, 0, stream>>>(E, uW, Wut);
    bias_kernel<<<(NNODE * 96 + 255) / 256, 256, 0, stream>>>(E, gb, ub, bg, bu);
    setup_kernel<<<NNODE * COLP / 256, 256, 0, stream>>>(src, Xs, Xs2, Hs);

    const dim3 mmgrid(COLP / 128, NNODE / 128, KSPLIT);
    for (int t = 0; t < NT; ++t) {
        mm_kernel<<<mmgrid, 256, 0, stream>>>(Ah, Xs, Y);
        gate_kernel<<<NNODE / 4, 256, 0, stream>>>(Xs, Y, Wgt, bg, Hs, Xs2, rb);
        mm_kernel<<<mmgrid, 256, 0, stream>>>(Ah, Xs2, Y);
        upd_kernel<<<NNODE / 4, 256, 0, stream>>>(Xs2, Y, Wut, bu, rb, src, Hs, Xs, t + 1);
    }
    out_kernel<<<NNODE, 256, 0, stream>>>(Hs, cw, cb, out);
}

// Round 6
// 1394.280 us; speedup vs baseline: 1.3145x; 1.3145x over previous
//
#include <hip/hip_runtime.h>
#include <hip/hip_bf16.h>
#include <math.h>

// Problem constants
// B=32, T=12, N=2048, C=1, D=10, K=2, H=32
// CH = C+H = 33, COLS = B*CH = 1056, padded to COLP = 1152 (=9*128)

#define NNODE 2048
#define NB 32
#define NT 12
#define NH 32
#define CH 33
#define COLS 1056
#define COLP 1152
#define ND 10
#define KPAD 96    // gconv K = 2*33 = 66, zero-padded to 3 MFMA k-tiles
#define GPAD 104   // LDS row stride (halfs) for cat tiles: 16B-aligned
#define WPAD 98    // LDS row stride (halfs) for wg/wu transpose: 49 dwords, coprime 32

// A is stored fp16 pre-scaled by ASCALE (power of 2, exact) to keep softmax
// tail entries out of fp16-denormal range; mm epilogue multiplies by 1/ASCALE.
#define ASCALE 256.0f
#define AINV 0.00390625f

// split-K factor for mm: 2048 = 4 * 512 -> grid 9*16*4 = 576 blocks
#define KSPLIT 4
#define KCHUNK 512
#define YSTRIDEH ((size_t)NNODE * COLP)  // one fp16 Y partial, in halfs

typedef _Float16 half8 __attribute__((ext_vector_type(8)));
typedef float floatx4 __attribute__((ext_vector_type(4)));

// ---------------- workspace layout (in float slots) ----------------
constexpr size_t OFF_AH  = 0;                           // Ah fp16 2048*2048
constexpr size_t OFF_WGT = OFF_AH + 2097152u;           // Wgt fp16 [n][64][96]
constexpr size_t OFF_WUT = OFF_WGT + 6291456u;          // Wut fp16 [n][32][96]
constexpr size_t OFF_BG  = OFF_WUT + 3145728u;          // bg fp32 2048*64
constexpr size_t OFF_BU  = OFF_BG + 131072u;            // bu fp32 2048*32
constexpr size_t OFF_XT  = OFF_BU + 65536u;             // XT fp16 [1152][2048]
constexpr size_t OFF_X2T = OFF_XT + 1179648u;           // X2T fp16 [1152][2048]
constexpr size_t OFF_HS  = OFF_X2T + 1179648u;          // Hs fp32 [2048][32*32]
constexpr size_t OFF_Y   = OFF_HS + 2097152u;           // Y fp16 4 x [2048][1152]
constexpr size_t OFF_R   = OFF_Y + 4718592u;            // rbuf fp16 2048*1024
constexpr size_t OFF_ZH  = OFF_R + 1048576u;            // zh fp16 2048*1024
// end = 23,003,136 floats = ~92 MB

// ---------------- A = softmax(relu(E E^T), axis=1) * ASCALE, stored fp16 ----------------
__global__ __launch_bounds__(256) void adj_kernel(const float* __restrict__ E,
                                                  _Float16* __restrict__ Ah) {
    __shared__ float En[ND];
    __shared__ float red[256];
    const int n = blockIdx.x;
    const int t = threadIdx.x;
    if (t < ND) En[t] = E[n * ND + t];
    __syncthreads();
    float v[8];
    float mx = 0.f;
#pragma unroll
    for (int i = 0; i < 8; ++i) {
        const int m = t + i * 256;
        float acc = 0.f;
#pragma unroll
        for (int d = 0; d < ND; ++d) acc += En[d] * E[m * ND + d];
        acc = fmaxf(acc, 0.f);
        v[i] = acc;
        mx = fmaxf(mx, acc);
    }
    red[t] = mx;
    __syncthreads();
    for (int s = 128; s > 0; s >>= 1) {
        if (t < s) red[t] = fmaxf(red[t], red[t + s]);
        __syncthreads();
    }
    mx = red[0];
    __syncthreads();
    float sum = 0.f;
#pragma unroll
    for (int i = 0; i < 8; ++i) {
        v[i] = expf(v[i] - mx);
        sum += v[i];
    }
    red[t] = sum;
    __syncthreads();
    for (int s = 128; s > 0; s >>= 1) {
        if (t < s) red[t] += red[t + s];
        __syncthreads();
    }
    const float inv = ASCALE / red[0];
#pragma unroll
    for (int i = 0; i < 8; ++i)
        Ah[(size_t)n * NNODE + t + i * 256] = (_Float16)(v[i] * inv);
}

// ---------------- per-node weights -> [n][o][k], coalesced via LDS transpose ----------------
// One block per node. Coalesced gW reads (consecutive rem), transpose in LDS
// (row stride 49 dwords -> conflict-free), coalesced dword writes out.
__global__ __launch_bounds__(256) void wg_kernel(const float* __restrict__ E,
                                                 const float* __restrict__ gW,
                                                 _Float16* __restrict__ Wgt) {
    __shared__ float Es[ND];
    __shared__ _Float16 Wl[64 * WPAD];  // 6272 halfs
    const int n = blockIdx.x, t = threadIdx.x;
    if (t < ND) Es[t] = E[n * ND + t];
    for (int i = t; i < 64 * WPAD / 2; i += 256) ((unsigned*)Wl)[i] = 0u;
    __syncthreads();
    for (int rem = t; rem < 4224; rem += 256) {
        float acc = 0.f;
#pragma unroll
        for (int d = 0; d < ND; ++d) acc += Es[d] * gW[d * 4224 + rem];
        const int kk = rem / 2112, r2 = rem % 2112;
        const int i = r2 >> 6, o = r2 & 63;
        Wl[o * WPAD + kk * 33 + i] = (_Float16)acc;
    }
    __syncthreads();
    const unsigned* wl = (const unsigned*)Wl;
    unsigned* dst = (unsigned*)(Wgt + (size_t)n * 6144);
    for (int idx = t; idx < 64 * 48; idx += 256) {
        const int o = idx / 48, j = idx % 48;
        dst[idx] = wl[o * (WPAD / 2) + j];
    }
}

__global__ __launch_bounds__(256) void wu_kernel(const float* __restrict__ E,
                                                 const float* __restrict__ uW,
                                                 _Float16* __restrict__ Wut) {
    __shared__ float Es[ND];
    __shared__ _Float16 Wl[32 * WPAD];  // 3136 halfs
    const int n = blockIdx.x, t = threadIdx.x;
    if (t < ND) Es[t] = E[n * ND + t];
    for (int i = t; i < 32 * WPAD / 2; i += 256) ((unsigned*)Wl)[i] = 0u;
    __syncthreads();
    for (int rem = t; rem < 2112; rem += 256) {
        float acc = 0.f;
#pragma unroll
        for (int d = 0; d < ND; ++d) acc += Es[d] * uW[d * 2112 + rem];
        const int kk = rem / 1056, r2 = rem % 1056;
        const int i = r2 >> 5, o = r2 & 31;
        Wl[o * WPAD + kk * 33 + i] = (_Float16)acc;
    }
    __syncthreads();
    const unsigned* wl = (const unsigned*)Wl;
    unsigned* dst = (unsigned*)(Wut + (size_t)n * 3072);
    for (int idx = t; idx < 32 * 48; idx += 256) {
        const int o = idx / 48, j = idx % 48;
        dst[idx] = wl[o * (WPAD / 2) + j];
    }
}

__global__ __launch_bounds__(256) void bias_kernel(const float* __restrict__ E,
                                                   const float* __restrict__ gb,
                                                   const float* __restrict__ ub,
                                                   float* __restrict__ bg,
                                                   float* __restrict__ bu) {
    const int idx = blockIdx.x * 256 + threadIdx.x;
    if (idx < NNODE * 64) {
        const int n = idx >> 6, o = idx & 63;
        float acc = 0.f;
#pragma unroll
        for (int d = 0; d < ND; ++d) acc += E[n * ND + d] * gb[d * 64 + o];
        bg[idx] = acc;
    } else if (idx < NNODE * 64 + NNODE * 32) {
        const int j = idx - NNODE * 64;
        const int n = j >> 5, o = j & 31;
        float acc = 0.f;
#pragma unroll
        for (int d = 0; d < ND; ++d) acc += E[n * ND + d] * ub[d * 32 + o];
        bu[j] = acc;
    }
}

// ---------------- init: XT = [x_0 cols | 0], X2T = 0, Hs = 0 ----------------
__global__ __launch_bounds__(256) void setup_kernel(const float* __restrict__ src,
                                                    _Float16* __restrict__ XT,
                                                    _Float16* __restrict__ X2T,
                                                    float* __restrict__ Hs) {
    const int idx = blockIdx.x * 256 + threadIdx.x;
    if (idx >= COLP * NNODE) return;
    const int c = idx / NNODE, n = idx % NNODE;
    _Float16 v = (_Float16)0.f;
    if (c < COLS && (c % CH) == 0)
        v = (_Float16)src[(size_t)(c / CH) * NT * NNODE + n];  // t = 0
    XT[idx] = v;
    X2T[idx] = (_Float16)0.f;
    if (idx < NNODE * 1024) Hs[idx] = 0.f;
}

// ---------------- Y_part[z] = (A*ASCALE) @ XT^T * (1/ASCALE), fp16 out ----------------
// Both operands k-contiguous: A [m][k], XT [c][k(=node)]. Symmetric staging,
// conflict-free b128 LDS writes, no transpose/pack VALU.
__global__ __launch_bounds__(256) void mm_kernel(const _Float16* __restrict__ Ah,
                                                 const _Float16* __restrict__ XT,
                                                 _Float16* __restrict__ Y) {
    __shared__ unsigned short As[128][40];  // [m][k]
    __shared__ unsigned short Bs[128][40];  // [c][k]
    const int t = threadIdx.x;
    const int m0 = blockIdx.y * 128;
    const int c0 = blockIdx.x * 128;
    const int kz = blockIdx.z;
    _Float16* __restrict__ Yp = Y + (size_t)kz * YSTRIDEH;
    const int lane = t & 63;
    const int w = t >> 6;
    const int wm = (w & 1) * 64;
    const int wn = (w >> 1) * 64;
    const int lm = lane & 15;
    const int q = lane >> 4;

    const int ar = t >> 1;         // staged row 0..127
    const int ac = (t & 1) * 16;   // 16-half chunk

    floatx4 acc[4][4] = {};

    const int kend = kz * KCHUNK + KCHUNK;
    for (int kt = kz * KCHUNK; kt < kend; kt += 32) {
        const _Float16* pa = Ah + (size_t)(m0 + ar) * NNODE + kt + ac;
        const _Float16* pb = XT + (size_t)(c0 + ar) * NNODE + kt + ac;
        uint4 a0 = *(const uint4*)pa;
        uint4 a1 = *(const uint4*)(pa + 8);
        uint4 b0 = *(const uint4*)pb;
        uint4 b1 = *(const uint4*)(pb + 8);
        *(uint4*)&As[ar][ac] = a0;
        *(uint4*)&As[ar][ac + 8] = a1;
        *(uint4*)&Bs[ar][ac] = b0;
        *(uint4*)&Bs[ar][ac + 8] = b1;
        __syncthreads();
        half8 af[4], bf[4];
#pragma unroll
        for (int mt = 0; mt < 4; ++mt)
            af[mt] = *(const half8*)&As[wm + mt * 16 + lm][q * 8];
#pragma unroll
        for (int nt = 0; nt < 4; ++nt)
            bf[nt] = *(const half8*)&Bs[wn + nt * 16 + lm][q * 8];
#pragma unroll
        for (int mt = 0; mt < 4; ++mt)
#pragma unroll
            for (int nt = 0; nt < 4; ++nt)
                acc[mt][nt] = __builtin_amdgcn_mfma_f32_16x16x32_f16(
                    af[mt], bf[nt], acc[mt][nt], 0, 0, 0);
        __syncthreads();
    }
#pragma unroll
    for (int mt = 0; mt < 4; ++mt) {
#pragma unroll
        for (int nt = 0; nt < 4; ++nt) {
            const int row = m0 + wm + mt * 16 + q * 4;
            const int col = c0 + wn + nt * 16 + lm;
#pragma unroll
            for (int r = 0; r < 4; ++r)
                Yp[(size_t)(row + r) * COLP + col] = (_Float16)(acc[mt][nt][r] * AINV);
        }
    }
}

// ---------------- gate: MFMA weight apply; writes X2T (scatter), zh, rbuf ----------------
// 4 nodes/block, 1 wave/node. cat[b][k]: 0 = x_t, 1..32 = h (from Hs), 33..65 = y, 66..95 = 0.
__global__ __launch_bounds__(256) void gate_kernel(const float* __restrict__ src, int tcur,
                                                   const _Float16* __restrict__ Y,
                                                   const _Float16* __restrict__ Wgt,
                                                   const float* __restrict__ bg,
                                                   const float* __restrict__ Hs,
                                                   _Float16* __restrict__ X2T,
                                                   _Float16* __restrict__ zh,
                                                   _Float16* __restrict__ rbuf) {
    __shared__ _Float16 catL[4][32][GPAD];
    const int t = threadIdx.x;
    const int n0 = blockIdx.x * 4;
    {
        const int pair = t >> 1, which = t & 1;
        const int nd = pair >> 5, b = pair & 31;
        const int n1 = n0 + nd;
        if (which == 0) {
            catL[nd][b][0] = (_Float16)src[((size_t)b * NT + tcur) * NNODE + n1];
            const float* hp = Hs + (size_t)n1 * 1024 + b * 32;
#pragma unroll
            for (int i = 0; i < 32; ++i) catL[nd][b][1 + i] = (_Float16)hp[i];
#pragma unroll
            for (int i = 66; i < KPAD; i += 2) *(unsigned*)&catL[nd][b][i] = 0u;
        } else {
            const _Float16* yp = Y + (size_t)n1 * COLP + b * CH;
#pragma unroll
            for (int i = 0; i < CH; ++i) {
                const float s = (float)yp[i] + (float)yp[YSTRIDEH + i] +
                                (float)yp[2 * YSTRIDEH + i] + (float)yp[3 * YSTRIDEH + i];
                catL[nd][b][CH + i] = (_Float16)s;
            }
        }
    }
    __syncthreads();
    const int w = t >> 6, lane = t & 63, lm = lane & 15, q = lane >> 4;
    const int n = n0 + w;
    const _Float16* Wn = Wgt + (size_t)n * 6144;
    floatx4 acc[2][4] = {};
#pragma unroll
    for (int kt = 0; kt < 3; ++kt) {
        half8 af[2], bf[4];
#pragma unroll
        for (int mt = 0; mt < 2; ++mt)
            af[mt] = *(const half8*)&catL[w][mt * 16 + lm][kt * 32 + q * 8];
#pragma unroll
        for (int nt = 0; nt < 4; ++nt)
            bf[nt] = *(const half8*)(Wn + (nt * 16 + lm) * KPAD + kt * 32 + q * 8);
#pragma unroll
        for (int mt = 0; mt < 2; ++mt)
#pragma unroll
            for (int nt = 0; nt < 4; ++nt)
                acc[mt][nt] = __builtin_amdgcn_mfma_f32_16x16x32_f16(
                    af[mt], bf[nt], acc[mt][nt], 0, 0, 0);
    }
#pragma unroll
    for (int nt = 0; nt < 4; ++nt) {
        const int o = nt * 16 + lm;
        const float bias = bg[n * 64 + o];
#pragma unroll
        for (int mt = 0; mt < 2; ++mt) {
#pragma unroll
            for (int r = 0; r < 4; ++r) {
                const int b = mt * 16 + q * 4 + r;
                const float s = 1.f / (1.f + expf(-(acc[mt][nt][r] + bias)));
                if (o < 32) {
                    const float hold = Hs[(size_t)n * 1024 + b * 32 + o];
                    const _Float16 zv = (_Float16)(s * hold);
                    zh[(size_t)n * 1024 + b * 32 + o] = zv;
                    X2T[(size_t)(b * CH + 1 + o) * NNODE + n] = zv;
                    if (o == 0)
                        X2T[(size_t)(b * CH) * NNODE + n] = catL[w][b][0];
                } else {
                    rbuf[(size_t)n * 1024 + b * 32 + (o - 32)] = (_Float16)s;
                }
            }
        }
    }
}

// ---------------- update: MFMA weight apply; writes Hs (fp32) + XT (scatter) ----------------
__global__ __launch_bounds__(256) void upd_kernel(const float* __restrict__ src,
                                                  int tcur, int tnext,
                                                  const _Float16* __restrict__ Y,
                                                  const _Float16* __restrict__ Wut,
                                                  const float* __restrict__ bu,
                                                  const _Float16* __restrict__ zh,
                                                  const _Float16* __restrict__ rbuf,
                                                  float* __restrict__ Hs,
                                                  _Float16* __restrict__ XT) {
    __shared__ _Float16 catL[4][32][GPAD];
    const int t = threadIdx.x;
    const int n0 = blockIdx.x * 4;
    {
        const int pair = t >> 1, which = t & 1;
        const int nd = pair >> 5, b = pair & 31;
        const int n1 = n0 + nd;
        if (which == 0) {
            catL[nd][b][0] = (_Float16)src[((size_t)b * NT + tcur) * NNODE + n1];
            const _Float16* zp = zh + (size_t)n1 * 1024 + b * 32;
#pragma unroll
            for (int i = 0; i < 32; ++i) catL[nd][b][1 + i] = zp[i];
#pragma unroll
            for (int i = 66; i < KPAD; i += 2) *(unsigned*)&catL[nd][b][i] = 0u;
        } else {
            const _Float16* yp = Y + (size_t)n1 * COLP + b * CH;
#pragma unroll
            for (int i = 0; i < CH; ++i) {
                const float s = (float)yp[i] + (float)yp[YSTRIDEH + i] +
                                (float)yp[2 * YSTRIDEH + i] + (float)yp[3 * YSTRIDEH + i];
                catL[nd][b][CH + i] = (_Float16)s;
            }
        }
    }
    __syncthreads();
    const int w = t >> 6, lane = t & 63, lm = lane & 15, q = lane >> 4;
    const int n = n0 + w;
    const _Float16* Wn = Wut + (size_t)n * 3072;
    floatx4 acc[2][2] = {};
#pragma unroll
    for (int kt = 0; kt < 3; ++kt) {
        half8 af[2], bf[2];
#pragma unroll
        for (int mt = 0; mt < 2; ++mt)
            af[mt] = *(const half8*)&catL[w][mt * 16 + lm][kt * 32 + q * 8];
#pragma unroll
        for (int nt = 0; nt < 2; ++nt)
            bf[nt] = *(const half8*)(Wn + (nt * 16 + lm) * KPAD + kt * 32 + q * 8);
#pragma unroll
        for (int mt = 0; mt < 2; ++mt)
#pragma unroll
            for (int nt = 0; nt < 2; ++nt)
                acc[mt][nt] = __builtin_amdgcn_mfma_f32_16x16x32_f16(
                    af[mt], bf[nt], acc[mt][nt], 0, 0, 0);
    }
#pragma unroll
    for (int nt = 0; nt < 2; ++nt) {
        const int o = nt * 16 + lm;
        const float bias = bu[n * 32 + o];
#pragma unroll
        for (int mt = 0; mt < 2; ++mt) {
#pragma unroll
            for (int r = 0; r < 4; ++r) {
                const int b = mt * 16 + q * 4 + r;
                const float hc = tanhf(acc[mt][nt][r] + bias);
                const float rr = (float)rbuf[(size_t)n * 1024 + b * 32 + o];
                const size_t hidx = (size_t)n * 1024 + b * 32 + o;
                const float hnew = rr * Hs[hidx] + (1.f - rr) * hc;
                Hs[hidx] = hnew;
                XT[(size_t)(b * CH + 1 + o) * NNODE + n] = (_Float16)hnew;
                if (o == 0 && tnext < NT)
                    XT[(size_t)(b * CH) * NNODE + n] =
                        (_Float16)src[((size_t)b * NT + tnext) * NNODE + n];
            }
        }
    }
}

// ---------------- out[b,0,n,t] = dot(h[b,n,:], convW[t,:]) + convb[t] ----------------
__global__ __launch_bounds__(256) void out_kernel(const float* __restrict__ Hs,
                                                  const float* __restrict__ cw,
                                                  const float* __restrict__ cb,
                                                  float* __restrict__ out) {
    __shared__ float h[NB * NH];
    __shared__ float cws[NT * NH];
    __shared__ float cbs[NT];
    const int n = blockIdx.x;
    const int t = threadIdx.x;
    for (int i = t; i < NT * NH; i += 256) cws[i] = cw[i];
    if (t < NT) cbs[t] = cb[t];
    for (int i = t; i < NB * NH; i += 256) h[i] = Hs[(size_t)n * 1024 + i];
    __syncthreads();
    for (int p = t; p < NB * NT; p += 256) {
        const int b = p / NT, tt = p % NT;
        float acc = cbs[tt];
#pragma unroll
        for (int j = 0; j < NH; ++j) acc += h[b * NH + j] * cws[tt * NH + j];
        out[(size_t)b * NNODE * NT + (size_t)n * NT + tt] = acc;
    }
}

extern "C" void kernel_launch(void* const* d_in, const int* in_sizes, int n_in,
                              void* d_out, int out_size, void* d_ws, size_t ws_size,
                              hipStream_t stream) {
    const float* src  = (const float*)d_in[0];
    const float* E    = (const float*)d_in[1];
    const float* gW   = (const float*)d_in[2];
    const float* gb   = (const float*)d_in[3];
    const float* uW   = (const float*)d_in[4];
    const float* ub   = (const float*)d_in[5];
    const float* cw   = (const float*)d_in[6];
    const float* cb   = (const float*)d_in[7];
    float* out = (float*)d_out;

    float* ws = (float*)d_ws;
    _Float16* Ah  = (_Float16*)(ws + OFF_AH);
    _Float16* Wgt = (_Float16*)(ws + OFF_WGT);
    _Float16* Wut = (_Float16*)(ws + OFF_WUT);
    float* bg  = ws + OFF_BG;
    float* bu  = ws + OFF_BU;
    _Float16* XT  = (_Float16*)(ws + OFF_XT);
    _Float16* X2T = (_Float16*)(ws + OFF_X2T);
    float* Hs  = ws + OFF_HS;
    _Float16* Y   = (_Float16*)(ws + OFF_Y);
    _Float16* rb  = (_Float16*)(ws + OFF_R);
    _Float16* zh  = (_Float16*)(ws + OFF_ZH);

    adj_kernel<<<NNODE, 256, 0, stream>>>(E, Ah);
    wg_kernel<<<NNODE, 256, 0, stream>>>(E, gW, Wgt);
    wu_kernel<<<NNODE, 256, 0, stream>>>(E, uW, Wut);
    bias_kernel<<<(NNODE * 96 + 255) / 256, 256, 0, stream>>>(E, gb, ub, bg, bu);
    setup_kernel<<<COLP * NNODE / 256, 256, 0, stream>>>(src, XT, X2T, Hs);

    const dim3 mmgrid(COLP / 128, NNODE / 128, KSPLIT);
    for (int t = 0; t < NT; ++t) {
        mm_kernel<<<mmgrid, 256, 0, stream>>>(Ah, XT, Y);
        gate_kernel<<<NNODE / 4, 256, 0, stream>>>(src, t, Y, Wgt, bg, Hs, X2T, zh, rb);
        mm_kernel<<<mmgrid, 256, 0, stream>>>(Ah, X2T, Y);
        upd_kernel<<<NNODE / 4, 256, 0, stream>>>(src, t, t + 1, Y, Wut, bu, zh, rb, Hs, XT);
    }
    out_kernel<<<NNODE, 256, 0, stream>>>(Hs, cw, cb, out);
}

// Round 8
// 1239.433 us; speedup vs baseline: 1.4788x; 1.1249x over previous
//
#include <hip/hip_runtime.h>
#include <hip/hip_bf16.h>
#include <math.h>

// Problem constants
// B=32, T=12, N=2048, C=1, D=10, K=2, H=32
// Recurrent mms operate on exactly the 1024 h-columns (col = b*32 + o).
// A@x_t for all t is precomputed once into AXP (384 cols).

#define NNODE 2048
#define NB 32
#define NT 12
#define NH 32
#define ND 10
#define NCOL 1024          // h columns
#define NCX 384            // (t,b) x columns
#define KPAD 96            // gconv K = 66, zero-padded to 3 MFMA k-tiles
#define GPAD 104           // LDS row stride (halfs) for cat tiles
#define WPAD 98            // LDS row stride for wg/wu transpose (49 dwords, coprime 32)

#define ASCALE 256.0f
#define AINV 0.00390625f

#define KSPLIT 4
#define KCHUNK 512
#define Y1S ((size_t)NNODE * NCOL)   // one Y partial (halfs)
#define AXPS ((size_t)NNODE * NCX)   // one AXP partial (halfs)

typedef _Float16 half8 __attribute__((ext_vector_type(8)));
typedef float floatx4 __attribute__((ext_vector_type(4)));

// ---------------- workspace layout (float slots) ----------------
constexpr size_t OFF_AH  = 0;                      // Ah fp16 [2048][2048]
constexpr size_t OFF_WGT = OFF_AH + 2097152u;      // Wgt fp16 [n][64][96]
constexpr size_t OFF_WUT = OFF_WGT + 6291456u;     // Wut fp16 [n][32][96]
constexpr size_t OFF_BG  = OFF_WUT + 3145728u;     // bg fp32 [2048][64]
constexpr size_t OFF_BU  = OFF_BG + 131072u;       // bu fp32 [2048][32]
constexpr size_t OFF_XT  = OFF_BU + 65536u;        // XT  fp16 [1024][2048]
constexpr size_t OFF_X2T = OFF_XT + 1048576u;      // X2T fp16 [1024][2048]
constexpr size_t OFF_SXT = OFF_X2T + 1048576u;     // SRCXT fp16 [384][2048]
constexpr size_t OFF_HS  = OFF_SXT + 393216u;      // Hs fp32 [2048][1024]
constexpr size_t OFF_Y   = OFF_HS + 2097152u;      // Y fp16 [4][2048][1024]
constexpr size_t OFF_AXP = OFF_Y + 4194304u;       // AXP fp16 [4][2048][384]
constexpr size_t OFF_R   = OFF_AXP + 1572864u;     // rbuf fp16 [2048][1024] -> 1,048,576 slots
constexpr size_t OFF_ZH  = OFF_R + 1048576u;       // zh   fp16 [2048][1024] -> 1,048,576 slots
// end = 24,182,784 floats = ~96.7 MB

// ---------------- A = softmax(relu(E E^T), axis=1) * ASCALE, fp16 ----------------
__global__ __launch_bounds__(256) void adj_kernel(const float* __restrict__ E,
                                                  _Float16* __restrict__ Ah) {
    __shared__ float En[ND];
    __shared__ float red[256];
    const int n = blockIdx.x;
    const int t = threadIdx.x;
    if (t < ND) En[t] = E[n * ND + t];
    __syncthreads();
    float v[8];
    float mx = 0.f;
#pragma unroll
    for (int i = 0; i < 8; ++i) {
        const int m = t + i * 256;
        float acc = 0.f;
#pragma unroll
        for (int d = 0; d < ND; ++d) acc += En[d] * E[m * ND + d];
        acc = fmaxf(acc, 0.f);
        v[i] = acc;
        mx = fmaxf(mx, acc);
    }
    red[t] = mx;
    __syncthreads();
    for (int s = 128; s > 0; s >>= 1) {
        if (t < s) red[t] = fmaxf(red[t], red[t + s]);
        __syncthreads();
    }
    mx = red[0];
    __syncthreads();
    float sum = 0.f;
#pragma unroll
    for (int i = 0; i < 8; ++i) {
        v[i] = expf(v[i] - mx);
        sum += v[i];
    }
    red[t] = sum;
    __syncthreads();
    for (int s = 128; s > 0; s >>= 1) {
        if (t < s) red[t] += red[t + s];
        __syncthreads();
    }
    const float inv = ASCALE / red[0];
#pragma unroll
    for (int i = 0; i < 8; ++i)
        Ah[(size_t)n * NNODE + t + i * 256] = (_Float16)(v[i] * inv);
}

// ---------------- per-node weights -> [n][o][k] via LDS transpose ----------------
__global__ __launch_bounds__(256) void wg_kernel(const float* __restrict__ E,
                                                 const float* __restrict__ gW,
                                                 _Float16* __restrict__ Wgt) {
    __shared__ float Es[ND];
    __shared__ _Float16 Wl[64 * WPAD];
    const int n = blockIdx.x, t = threadIdx.x;
    if (t < ND) Es[t] = E[n * ND + t];
    for (int i = t; i < 64 * WPAD / 2; i += 256) ((unsigned*)Wl)[i] = 0u;
    __syncthreads();
    for (int rem = t; rem < 4224; rem += 256) {
        float acc = 0.f;
#pragma unroll
        for (int d = 0; d < ND; ++d) acc += Es[d] * gW[d * 4224 + rem];
        const int kk = rem / 2112, r2 = rem % 2112;
        const int i = r2 >> 6, o = r2 & 63;
        Wl[o * WPAD + kk * 33 + i] = (_Float16)acc;
    }
    __syncthreads();
    const unsigned* wl = (const unsigned*)Wl;
    unsigned* dst = (unsigned*)(Wgt + (size_t)n * 6144);
    for (int idx = t; idx < 64 * 48; idx += 256) {
        const int o = idx / 48, j = idx % 48;
        dst[idx] = wl[o * (WPAD / 2) + j];
    }
}

__global__ __launch_bounds__(256) void wu_kernel(const float* __restrict__ E,
                                                 const float* __restrict__ uW,
                                                 _Float16* __restrict__ Wut) {
    __shared__ float Es[ND];
    __shared__ _Float16 Wl[32 * WPAD];
    const int n = blockIdx.x, t = threadIdx.x;
    if (t < ND) Es[t] = E[n * ND + t];
    for (int i = t; i < 32 * WPAD / 2; i += 256) ((unsigned*)Wl)[i] = 0u;
    __syncthreads();
    for (int rem = t; rem < 2112; rem += 256) {
        float acc = 0.f;
#pragma unroll
        for (int d = 0; d < ND; ++d) acc += Es[d] * uW[d * 2112 + rem];
        const int kk = rem / 1056, r2 = rem % 1056;
        const int i = r2 >> 5, o = r2 & 31;
        Wl[o * WPAD + kk * 33 + i] = (_Float16)acc;
    }
    __syncthreads();
    const unsigned* wl = (const unsigned*)Wl;
    unsigned* dst = (unsigned*)(Wut + (size_t)n * 3072);
    for (int idx = t; idx < 32 * 48; idx += 256) {
        const int o = idx / 48, j = idx % 48;
        dst[idx] = wl[o * (WPAD / 2) + j];
    }
}

__global__ __launch_bounds__(256) void bias_kernel(const float* __restrict__ E,
                                                   const float* __restrict__ gb,
                                                   const float* __restrict__ ub,
                                                   float* __restrict__ bg,
                                                   float* __restrict__ bu) {
    const int idx = blockIdx.x * 256 + threadIdx.x;
    if (idx < NNODE * 64) {
        const int n = idx >> 6, o = idx & 63;
        float acc = 0.f;
#pragma unroll
        for (int d = 0; d < ND; ++d) acc += E[n * ND + d] * gb[d * 64 + o];
        bg[idx] = acc;
    } else if (idx < NNODE * 64 + NNODE * 32) {
        const int j = idx - NNODE * 64;
        const int n = j >> 5, o = j & 31;
        float acc = 0.f;
#pragma unroll
        for (int d = 0; d < ND; ++d) acc += E[n * ND + d] * ub[d * 32 + o];
        bu[j] = acc;
    }
}

// ---------------- init: XT=0, X2T=0, Hs=0, SRCXT[(t*32+b)][n] = src[b][t][n] ----------------
__global__ __launch_bounds__(256) void setup_kernel(const float* __restrict__ src,
                                                    _Float16* __restrict__ XT,
                                                    _Float16* __restrict__ X2T,
                                                    _Float16* __restrict__ SXT,
                                                    float* __restrict__ Hs) {
    const int idx = blockIdx.x * 256 + threadIdx.x;  // over 2048*1024
    XT[idx] = (_Float16)0.f;
    X2T[idx] = (_Float16)0.f;
    Hs[idx] = 0.f;
    if (idx < NCX * NNODE) {
        const int col = idx / NNODE, n = idx % NNODE;
        const int tt = col >> 5, b = col & 31;
        SXT[idx] = (_Float16)src[((size_t)b * NT + tt) * NNODE + n];
    }
}

// ---------------- Y_part[z] = (A*ASCALE) @ XT^T * (1/ASCALE), fp16 out ----------------
// 1-D grid, 64*nct blocks: xcd = bid&7 pins split z = xcd>>1 to one XCD-pair so
// the 2 MB A k-slice (+XT slice) stays L2-resident. Both operands k-contig.
__global__ __launch_bounds__(256) void mm_kernel(const _Float16* __restrict__ Ah,
                                                 const _Float16* __restrict__ XT,
                                                 _Float16* __restrict__ Y, int nct) {
    __shared__ unsigned short As[128][40];
    __shared__ unsigned short Bs[128][40];
    const int t = threadIdx.x;
    const int bid = blockIdx.x;
    const int xcd = bid & 7;
    const int kz = xcd >> 1;
    const int s = (bid >> 3) * 2 + (xcd & 1);  // [0, 16*nct)
    const int m0 = (s & 15) * 128;
    const int c0 = (s >> 4) * 128;
    const int ncols = nct << 7;
    _Float16* __restrict__ Yp = Y + (size_t)kz * NNODE * ncols;
    const int lane = t & 63;
    const int w = t >> 6;
    const int wm = (w & 1) * 64;
    const int wn = (w >> 1) * 64;
    const int lm = lane & 15;
    const int q = lane >> 4;

    const int ar = t >> 1;
    const int ac = (t & 1) * 16;

    floatx4 acc[4][4] = {};

    const int kend = kz * KCHUNK + KCHUNK;
    for (int kt = kz * KCHUNK; kt < kend; kt += 32) {
        const _Float16* pa = Ah + (size_t)(m0 + ar) * NNODE + kt + ac;
        const _Float16* pb = XT + (size_t)(c0 + ar) * NNODE + kt + ac;
        uint4 a0 = *(const uint4*)pa;
        uint4 a1 = *(const uint4*)(pa + 8);
        uint4 b0 = *(const uint4*)pb;
        uint4 b1 = *(const uint4*)(pb + 8);
        *(uint4*)&As[ar][ac] = a0;
        *(uint4*)&As[ar][ac + 8] = a1;
        *(uint4*)&Bs[ar][ac] = b0;
        *(uint4*)&Bs[ar][ac + 8] = b1;
        __syncthreads();
        half8 af[4], bf[4];
#pragma unroll
        for (int mt = 0; mt < 4; ++mt)
            af[mt] = *(const half8*)&As[wm + mt * 16 + lm][q * 8];
#pragma unroll
        for (int nt = 0; nt < 4; ++nt)
            bf[nt] = *(const half8*)&Bs[wn + nt * 16 + lm][q * 8];
#pragma unroll
        for (int mt = 0; mt < 4; ++mt)
#pragma unroll
            for (int nt = 0; nt < 4; ++nt)
                acc[mt][nt] = __builtin_amdgcn_mfma_f32_16x16x32_f16(
                    af[mt], bf[nt], acc[mt][nt], 0, 0, 0);
        __syncthreads();
    }
#pragma unroll
    for (int mt = 0; mt < 4; ++mt) {
#pragma unroll
        for (int nt = 0; nt < 4; ++nt) {
            const int row = m0 + wm + mt * 16 + q * 4;
            const int col = c0 + wn + nt * 16 + lm;
#pragma unroll
            for (int r = 0; r < 4; ++r)
                Yp[(size_t)(row + r) * ncols + col] = (_Float16)(acc[mt][nt][r] * AINV);
        }
    }
}

// ---------------- gate: MFMA weight apply; writes X2T (h-cols), zh, rbuf ----------------
// cat[b][k]: 0 = x_t (src), 1..32 = h (Hs), 33 = A@x (AXP), 34..65 = A@h (Y), 66..95 = 0.
__global__ __launch_bounds__(256) void gate_kernel(const float* __restrict__ src, int tcur,
                                                   const _Float16* __restrict__ Y,
                                                   const _Float16* __restrict__ AXP,
                                                   const _Float16* __restrict__ Wgt,
                                                   const float* __restrict__ bg,
                                                   const float* __restrict__ Hs,
                                                   _Float16* __restrict__ X2T,
                                                   _Float16* __restrict__ zh,
                                                   _Float16* __restrict__ rbuf) {
    __shared__ _Float16 catL[4][32][GPAD];
    const int t = threadIdx.x;
    const int n0 = blockIdx.x * 4;
    {
        const int pair = t >> 1, which = t & 1;
        const int nd = pair >> 5, b = pair & 31;
        const int n1 = n0 + nd;
        if (which == 0) {
            catL[nd][b][0] = (_Float16)src[((size_t)b * NT + tcur) * NNODE + n1];
            const float* hp = Hs + (size_t)n1 * 1024 + b * 32;
#pragma unroll
            for (int i = 0; i < 32; ++i) catL[nd][b][1 + i] = (_Float16)hp[i];
#pragma unroll
            for (int i = 66; i < KPAD; i += 2) *(unsigned*)&catL[nd][b][i] = 0u;
        } else {
            const _Float16* ax = AXP + (size_t)n1 * NCX + tcur * 32 + b;
            catL[nd][b][33] = (_Float16)((float)ax[0] + (float)ax[AXPS] +
                                         (float)ax[2 * AXPS] + (float)ax[3 * AXPS]);
            const _Float16* yp = Y + (size_t)n1 * NCOL + b * 32;
#pragma unroll
            for (int i = 0; i < 32; ++i) {
                const float sv = (float)yp[i] + (float)yp[Y1S + i] +
                                 (float)yp[2 * Y1S + i] + (float)yp[3 * Y1S + i];
                catL[nd][b][34 + i] = (_Float16)sv;
            }
        }
    }
    __syncthreads();
    const int w = t >> 6, lane = t & 63, lm = lane & 15, q = lane >> 4;
    const int n = n0 + w;
    const _Float16* Wn = Wgt + (size_t)n * 6144;
    floatx4 acc[2][4] = {};
#pragma unroll
    for (int kt = 0; kt < 3; ++kt) {
        half8 af[2], bf[4];
#pragma unroll
        for (int mt = 0; mt < 2; ++mt)
            af[mt] = *(const half8*)&catL[w][mt * 16 + lm][kt * 32 + q * 8];
#pragma unroll
        for (int nt = 0; nt < 4; ++nt)
            bf[nt] = *(const half8*)(Wn + (nt * 16 + lm) * KPAD + kt * 32 + q * 8);
#pragma unroll
        for (int mt = 0; mt < 2; ++mt)
#pragma unroll
            for (int nt = 0; nt < 4; ++nt)
                acc[mt][nt] = __builtin_amdgcn_mfma_f32_16x16x32_f16(
                    af[mt], bf[nt], acc[mt][nt], 0, 0, 0);
    }
#pragma unroll
    for (int nt = 0; nt < 4; ++nt) {
        const int o = nt * 16 + lm;
        const float bias = bg[n * 64 + o];
#pragma unroll
        for (int mt = 0; mt < 2; ++mt) {
#pragma unroll
            for (int r = 0; r < 4; ++r) {
                const int b = mt * 16 + q * 4 + r;
                const float s = 1.f / (1.f + expf(-(acc[mt][nt][r] + bias)));
                if (o < 32) {
                    const float hold = Hs[(size_t)n * 1024 + b * 32 + o];
                    const _Float16 zv = (_Float16)(s * hold);
                    zh[(size_t)n * 1024 + b * 32 + o] = zv;
                    X2T[(size_t)(b * 32 + o) * NNODE + n] = zv;
                } else {
                    rbuf[(size_t)n * 1024 + b * 32 + (o - 32)] = (_Float16)s;
                }
            }
        }
    }
}

// ---------------- update: MFMA weight apply; writes Hs (fp32) + XT (h-cols) ----------------
__global__ __launch_bounds__(256) void upd_kernel(const float* __restrict__ src, int tcur,
                                                  const _Float16* __restrict__ Y,
                                                  const _Float16* __restrict__ AXP,
                                                  const _Float16* __restrict__ Wut,
                                                  const float* __restrict__ bu,
                                                  const _Float16* __restrict__ zh,
                                                  const _Float16* __restrict__ rbuf,
                                                  float* __restrict__ Hs,
                                                  _Float16* __restrict__ XT) {
    __shared__ _Float16 catL[4][32][GPAD];
    const int t = threadIdx.x;
    const int n0 = blockIdx.x * 4;
    {
        const int pair = t >> 1, which = t & 1;
        const int nd = pair >> 5, b = pair & 31;
        const int n1 = n0 + nd;
        if (which == 0) {
            catL[nd][b][0] = (_Float16)src[((size_t)b * NT + tcur) * NNODE + n1];
            const _Float16* zp = zh + (size_t)n1 * 1024 + b * 32;
#pragma unroll
            for (int i = 0; i < 32; ++i) catL[nd][b][1 + i] = zp[i];
#pragma unroll
            for (int i = 66; i < KPAD; i += 2) *(unsigned*)&catL[nd][b][i] = 0u;
        } else {
            const _Float16* ax = AXP + (size_t)n1 * NCX + tcur * 32 + b;
            catL[nd][b][33] = (_Float16)((float)ax[0] + (float)ax[AXPS] +
                                         (float)ax[2 * AXPS] + (float)ax[3 * AXPS]);
            const _Float16* yp = Y + (size_t)n1 * NCOL + b * 32;
#pragma unroll
            for (int i = 0; i < 32; ++i) {
                const float sv = (float)yp[i] + (float)yp[Y1S + i] +
                                 (float)yp[2 * Y1S + i] + (float)yp[3 * Y1S + i];
                catL[nd][b][34 + i] = (_Float16)sv;
            }
        }
    }
    __syncthreads();
    const int w = t >> 6, lane = t & 63, lm = lane & 15, q = lane >> 4;
    const int n = n0 + w;
    const _Float16* Wn = Wut + (size_t)n * 3072;
    floatx4 acc[2][2] = {};
#pragma unroll
    for (int kt = 0; kt < 3; ++kt) {
        half8 af[2], bf[2];
#pragma unroll
        for (int mt = 0; mt < 2; ++mt)
            af[mt] = *(const half8*)&catL[w][mt * 16 + lm][kt * 32 + q * 8];
#pragma unroll
        for (int nt = 0; nt < 2; ++nt)
            bf[nt] = *(const half8*)(Wn + (nt * 16 + lm) * KPAD + kt * 32 + q * 8);
#pragma unroll
        for (int mt = 0; mt < 2; ++mt)
#pragma unroll
            for (int nt = 0; nt < 2; ++nt)
                acc[mt][nt] = __builtin_amdgcn_mfma_f32_16x16x32_f16(
                    af[mt], bf[nt], acc[mt][nt], 0, 0, 0);
    }
#pragma unroll
    for (int nt = 0; nt < 2; ++nt) {
        const int o = nt * 16 + lm;
        const float bias = bu[n * 32 + o];
#pragma unroll
        for (int mt = 0; mt < 2; ++mt) {
#pragma unroll
            for (int r = 0; r < 4; ++r) {
                const int b = mt * 16 + q * 4 + r;
                const float hc = tanhf(acc[mt][nt][r] + bias);
                const float rr = (float)rbuf[(size_t)n * 1024 + b * 32 + o];
                const size_t hidx = (size_t)n * 1024 + b * 32 + o;
                const float hnew = rr * Hs[hidx] + (1.f - rr) * hc;
                Hs[hidx] = hnew;
                XT[(size_t)(b * 32 + o) * NNODE + n] = (_Float16)hnew;
            }
        }
    }
}

// ---------------- out[b,0,n,t] = dot(h[b,n,:], convW[t,:]) + convb[t] ----------------
__global__ __launch_bounds__(256) void out_kernel(const float* __restrict__ Hs,
                                                  const float* __restrict__ cw,
                                                  const float* __restrict__ cb,
                                                  float* __restrict__ out) {
    __shared__ float h[NB * NH];
    __shared__ float cws[NT * NH];
    __shared__ float cbs[NT];
    const int n = blockIdx.x;
    const int t = threadIdx.x;
    for (int i = t; i < NT * NH; i += 256) cws[i] = cw[i];
    if (t < NT) cbs[t] = cb[t];
    for (int i = t; i < NB * NH; i += 256) h[i] = Hs[(size_t)n * 1024 + i];
    __syncthreads();
    for (int p = t; p < NB * NT; p += 256) {
        const int b = p / NT, tt = p % NT;
        float acc = cbs[tt];
#pragma unroll
        for (int j = 0; j < NH; ++j) acc += h[b * NH + j] * cws[tt * NH + j];
        out[(size_t)b * NNODE * NT + (size_t)n * NT + tt] = acc;
    }
}

extern "C" void kernel_launch(void* const* d_in, const int* in_sizes, int n_in,
                              void* d_out, int out_size, void* d_ws, size_t ws_size,
                              hipStream_t stream) {
    const float* src  = (const float*)d_in[0];
    const float* E    = (const float*)d_in[1];
    const float* gW   = (const float*)d_in[2];
    const float* gb   = (const float*)d_in[3];
    const float* uW   = (const float*)d_in[4];
    const float* ub   = (const float*)d_in[5];
    const float* cw   = (const float*)d_in[6];
    const float* cb   = (const float*)d_in[7];
    float* out = (float*)d_out;

    float* ws = (float*)d_ws;
    _Float16* Ah  = (_Float16*)(ws + OFF_AH);
    _Float16* Wgt = (_Float16*)(ws + OFF_WGT);
    _Float16* Wut = (_Float16*)(ws + OFF_WUT);
    float* bg  = ws + OFF_BG;
    float* bu  = ws + OFF_BU;
    _Float16* XT  = (_Float16*)(ws + OFF_XT);
    _Float16* X2T = (_Float16*)(ws + OFF_X2T);
    _Float16* SXT = (_Float16*)(ws + OFF_SXT);
    float* Hs  = ws + OFF_HS;
    _Float16* Y   = (_Float16*)(ws + OFF_Y);
    _Float16* AXP = (_Float16*)(ws + OFF_AXP);
    _Float16* rb  = (_Float16*)(ws + OFF_R);
    _Float16* zh  = (_Float16*)(ws + OFF_ZH);

    adj_kernel<<<NNODE, 256, 0, stream>>>(E, Ah);
    wg_kernel<<<NNODE, 256, 0, stream>>>(E, gW, Wgt);
    wu_kernel<<<NNODE, 256, 0, stream>>>(E, uW, Wut);
    bias_kernel<<<(NNODE * 96 + 255) / 256, 256, 0, stream>>>(E, gb, ub, bg, bu);
    setup_kernel<<<NNODE * NCOL / 256, 256, 0, stream>>>(src, XT, X2T, SXT, Hs);

    // A @ x_t for all 12 steps at once (384 cols, 3 col-tiles)
    mm_kernel<<<64 * 3, 256, 0, stream>>>(Ah, SXT, AXP, 3);

    for (int t = 0; t < NT; ++t) {
        mm_kernel<<<64 * 8, 256, 0, stream>>>(Ah, XT, Y, 8);
        gate_kernel<<<NNODE / 4, 256, 0, stream>>>(src, t, Y, AXP, Wgt, bg, Hs, X2T, zh, rb);
        mm_kernel<<<64 * 8, 256, 0, stream>>>(Ah, X2T, Y, 8);
        upd_kernel<<<NNODE / 4, 256, 0, stream>>>(src, t, Y, AXP, Wut, bu, zh, rb, Hs, XT);
    }
    out_kernel<<<NNODE, 256, 0, stream>>>(Hs, cw, cb, out);
}

// Round 9
// 1166.836 us; speedup vs baseline: 1.5708x; 1.0622x over previous
//
#include <hip/hip_runtime.h>
#include <hip/hip_bf16.h>
#include <math.h>

// Problem constants
// B=32, T=12, N=2048, C=1, D=10, K=2, H=32
// Recurrent mms operate on exactly the 1024 h-columns (col = b*32 + o).
// A@x_t for all t is precomputed once into AXP (384 cols).

#define NNODE 2048
#define NB 32
#define NT 12
#define NH 32
#define ND 10
#define NCOL 1024          // h columns
#define NCX 384            // (t,b) x columns
#define KPAD 96            // gconv K = 66, zero-padded to 3 MFMA k-tiles
#define GPAD 104           // LDS row stride (halfs) for cat tiles
#define WPAD 98            // LDS row stride for wg/wu transpose (49 dwords, coprime 32)

#define ASCALE 256.0f
#define AINV 0.00390625f

#define KSPLIT 4
#define KCHUNK 512
#define Y1S ((size_t)NNODE * NCOL)   // one Y partial (halfs)
#define AXPS ((size_t)NNODE * NCX)   // one AXP partial (halfs)

typedef _Float16 half8 __attribute__((ext_vector_type(8)));
typedef float floatx4 __attribute__((ext_vector_type(4)));

#define AS1 __attribute__((address_space(1)))
#define AS3 __attribute__((address_space(3)))
// async global->LDS DMA, 16 B per lane, LDS dest = wave-uniform base + lane*16
__device__ __forceinline__ void gload16(const _Float16* g, _Float16* l) {
    __builtin_amdgcn_global_load_lds((const AS1 unsigned int*)(g),
                                     (AS3 unsigned int*)(l), 16, 0, 0);
}

// ---------------- workspace layout (float slots) ----------------
constexpr size_t OFF_AH  = 0;                      // Ah fp16 [2048][2048]
constexpr size_t OFF_WGT = OFF_AH + 2097152u;      // Wgt fp16 [n][64][96]
constexpr size_t OFF_WUT = OFF_WGT + 6291456u;     // Wut fp16 [n][32][96]
constexpr size_t OFF_BG  = OFF_WUT + 3145728u;     // bg fp32 [2048][64]
constexpr size_t OFF_BU  = OFF_BG + 131072u;       // bu fp32 [2048][32]
constexpr size_t OFF_XT  = OFF_BU + 65536u;        // XT  fp16 [1024][2048]
constexpr size_t OFF_X2T = OFF_XT + 1048576u;      // X2T fp16 [1024][2048]
constexpr size_t OFF_SXT = OFF_X2T + 1048576u;     // SRCXT fp16 [384][2048]
constexpr size_t OFF_HS  = OFF_SXT + 393216u;      // Hs fp32 [2048][1024]
constexpr size_t OFF_Y   = OFF_HS + 2097152u;      // Y fp16 [4][2048][1024]
constexpr size_t OFF_AXP = OFF_Y + 4194304u;       // AXP fp16 [4][2048][384]
constexpr size_t OFF_R   = OFF_AXP + 1572864u;     // rbuf fp16 [2048][1024] -> 1,048,576 slots
constexpr size_t OFF_ZH  = OFF_R + 1048576u;       // zh   fp16 [2048][1024] -> 1,048,576 slots
// end = 24,182,784 floats = ~96.7 MB

// ---------------- A = softmax(relu(E E^T), axis=1) * ASCALE, fp16 ----------------
__global__ __launch_bounds__(256) void adj_kernel(const float* __restrict__ E,
                                                  _Float16* __restrict__ Ah) {
    __shared__ float En[ND];
    __shared__ float red[256];
    const int n = blockIdx.x;
    const int t = threadIdx.x;
    if (t < ND) En[t] = E[n * ND + t];
    __syncthreads();
    float v[8];
    float mx = 0.f;
#pragma unroll
    for (int i = 0; i < 8; ++i) {
        const int m = t + i * 256;
        float acc = 0.f;
#pragma unroll
        for (int d = 0; d < ND; ++d) acc += En[d] * E[m * ND + d];
        acc = fmaxf(acc, 0.f);
        v[i] = acc;
        mx = fmaxf(mx, acc);
    }
    red[t] = mx;
    __syncthreads();
    for (int s = 128; s > 0; s >>= 1) {
        if (t < s) red[t] = fmaxf(red[t], red[t + s]);
        __syncthreads();
    }
    mx = red[0];
    __syncthreads();
    float sum = 0.f;
#pragma unroll
    for (int i = 0; i < 8; ++i) {
        v[i] = expf(v[i] - mx);
        sum += v[i];
    }
    red[t] = sum;
    __syncthreads();
    for (int s = 128; s > 0; s >>= 1) {
        if (t < s) red[t] += red[t + s];
        __syncthreads();
    }
    const float inv = ASCALE / red[0];
#pragma unroll
    for (int i = 0; i < 8; ++i)
        Ah[(size_t)n * NNODE + t + i * 256] = (_Float16)(v[i] * inv);
}

// ---------------- per-node weights -> [n][o][k] via LDS transpose ----------------
__global__ __launch_bounds__(256) void wg_kernel(const float* __restrict__ E,
                                                 const float* __restrict__ gW,
                                                 _Float16* __restrict__ Wgt) {
    __shared__ float Es[ND];
    __shared__ _Float16 Wl[64 * WPAD];
    const int n = blockIdx.x, t = threadIdx.x;
    if (t < ND) Es[t] = E[n * ND + t];
    for (int i = t; i < 64 * WPAD / 2; i += 256) ((unsigned*)Wl)[i] = 0u;
    __syncthreads();
    for (int rem = t; rem < 4224; rem += 256) {
        float acc = 0.f;
#pragma unroll
        for (int d = 0; d < ND; ++d) acc += Es[d] * gW[d * 4224 + rem];
        const int kk = rem / 2112, r2 = rem % 2112;
        const int i = r2 >> 6, o = r2 & 63;
        Wl[o * WPAD + kk * 33 + i] = (_Float16)acc;
    }
    __syncthreads();
    const unsigned* wl = (const unsigned*)Wl;
    unsigned* dst = (unsigned*)(Wgt + (size_t)n * 6144);
    for (int idx = t; idx < 64 * 48; idx += 256) {
        const int o = idx / 48, j = idx % 48;
        dst[idx] = wl[o * (WPAD / 2) + j];
    }
}

__global__ __launch_bounds__(256) void wu_kernel(const float* __restrict__ E,
                                                 const float* __restrict__ uW,
                                                 _Float16* __restrict__ Wut) {
    __shared__ float Es[ND];
    __shared__ _Float16 Wl[32 * WPAD];
    const int n = blockIdx.x, t = threadIdx.x;
    if (t < ND) Es[t] = E[n * ND + t];
    for (int i = t; i < 32 * WPAD / 2; i += 256) ((unsigned*)Wl)[i] = 0u;
    __syncthreads();
    for (int rem = t; rem < 2112; rem += 256) {
        float acc = 0.f;
#pragma unroll
        for (int d = 0; d < ND; ++d) acc += Es[d] * uW[d * 2112 + rem];
        const int kk = rem / 1056, r2 = rem % 1056;
        const int i = r2 >> 5, o = r2 & 31;
        Wl[o * WPAD + kk * 33 + i] = (_Float16)acc;
    }
    __syncthreads();
    const unsigned* wl = (const unsigned*)Wl;
    unsigned* dst = (unsigned*)(Wut + (size_t)n * 3072);
    for (int idx = t; idx < 32 * 48; idx += 256) {
        const int o = idx / 48, j = idx % 48;
        dst[idx] = wl[o * (WPAD / 2) + j];
    }
}

__global__ __launch_bounds__(256) void bias_kernel(const float* __restrict__ E,
                                                   const float* __restrict__ gb,
                                                   const float* __restrict__ ub,
                                                   float* __restrict__ bg,
                                                   float* __restrict__ bu) {
    const int idx = blockIdx.x * 256 + threadIdx.x;
    if (idx < NNODE * 64) {
        const int n = idx >> 6, o = idx & 63;
        float acc = 0.f;
#pragma unroll
        for (int d = 0; d < ND; ++d) acc += E[n * ND + d] * gb[d * 64 + o];
        bg[idx] = acc;
    } else if (idx < NNODE * 64 + NNODE * 32) {
        const int j = idx - NNODE * 64;
        const int n = j >> 5, o = j & 31;
        float acc = 0.f;
#pragma unroll
        for (int d = 0; d < ND; ++d) acc += E[n * ND + d] * ub[d * 32 + o];
        bu[j] = acc;
    }
}

// ---------------- init: XT=0, X2T=0, Hs=0, SRCXT[(t*32+b)][n] = src[b][t][n] ----------------
__global__ __launch_bounds__(256) void setup_kernel(const float* __restrict__ src,
                                                    _Float16* __restrict__ XT,
                                                    _Float16* __restrict__ X2T,
                                                    _Float16* __restrict__ SXT,
                                                    float* __restrict__ Hs) {
    const int idx = blockIdx.x * 256 + threadIdx.x;  // over 2048*1024
    XT[idx] = (_Float16)0.f;
    X2T[idx] = (_Float16)0.f;
    Hs[idx] = 0.f;
    if (idx < NCX * NNODE) {
        const int col = idx / NNODE, n = idx % NNODE;
        const int tt = col >> 5, b = col & 31;
        SXT[idx] = (_Float16)src[((size_t)b * NT + tt) * NNODE + n];
    }
}

// ---------------- Y_part[z] = (A*ASCALE) @ XT^T * (1/ASCALE), fp16 out ----------------
// 1-D grid, 64*nct blocks: xcd = bid&7 pins split z = xcd>>1 to one XCD-pair.
// Staging via global_load_lds (16 B/lane DMA, no VGPR round-trip). LDS layout:
// unpadded [row][32 halfs], 16B chunks XOR-swizzled: physical p = q ^ ((row>>1)&3)
// -> fragment reads are 2-way-bank-aliased only (free), DMA dest is lane-contiguous.
__global__ __launch_bounds__(256) void mm_kernel(const _Float16* __restrict__ Ah,
                                                 const _Float16* __restrict__ XT,
                                                 _Float16* __restrict__ Y, int nct) {
    __shared__ _Float16 As[128 * 32];
    __shared__ _Float16 Bs[128 * 32];
    const int t = threadIdx.x;
    const int bid = blockIdx.x;
    const int xcd = bid & 7;
    const int kz = xcd >> 1;
    const int s = (bid >> 3) * 2 + (xcd & 1);  // [0, 16*nct)
    const int m0 = (s & 15) * 128;
    const int c0 = (s >> 4) * 128;
    const int ncols = nct << 7;
    _Float16* __restrict__ Yp = Y + (size_t)kz * NNODE * ncols;
    const int lane = t & 63;
    const int w = t >> 6;
    const int wm = (w & 1) * 64;
    const int wn = (w >> 1) * 64;
    const int lm = lane & 15;
    const int q = lane >> 4;

    // staging: wave w DMAs rows [w*32, w*32+32) of both tiles (2 instrs each).
    // lane covers (local row = lane>>2, physical chunk = lane&3); global source
    // column is the logical chunk sq = p ^ ((row>>1)&3) = (lane&3)^((lane>>3)&3).
    const int srow = w * 32 + (lane >> 2);
    const int sq = (lane & 3) ^ ((lane >> 3) & 3);
    const _Float16* gA = Ah + (size_t)(m0 + srow) * NNODE + kz * KCHUNK + sq * 8;
    const _Float16* gB = XT + (size_t)(c0 + srow) * NNODE + kz * KCHUNK + sq * 8;
    _Float16* lA = As + w * 1024;  // w*32 rows * 32 halfs
    _Float16* lB = Bs + w * 1024;

    // fragment-read swizzle: physical chunk offset for logical chunk q
    const int fp = (q ^ ((lm >> 1) & 3)) * 8;

    floatx4 acc[4][4] = {};

    for (int kt = 0; kt < KCHUNK; kt += 32) {
        gload16(gA, lA);
        gload16(gA + 16 * NNODE, lA + 512);
        gload16(gB, lB);
        gload16(gB + 16 * NNODE, lB + 512);
        gA += 32;
        gB += 32;
        __syncthreads();
        half8 af[4], bf[4];
#pragma unroll
        for (int mt = 0; mt < 4; ++mt)
            af[mt] = *(const half8*)&As[(wm + mt * 16 + lm) * 32 + fp];
#pragma unroll
        for (int nt = 0; nt < 4; ++nt)
            bf[nt] = *(const half8*)&Bs[(wn + nt * 16 + lm) * 32 + fp];
#pragma unroll
        for (int mt = 0; mt < 4; ++mt)
#pragma unroll
            for (int nt = 0; nt < 4; ++nt)
                acc[mt][nt] = __builtin_amdgcn_mfma_f32_16x16x32_f16(
                    af[mt], bf[nt], acc[mt][nt], 0, 0, 0);
        __syncthreads();
    }
#pragma unroll
    for (int mt = 0; mt < 4; ++mt) {
#pragma unroll
        for (int nt = 0; nt < 4; ++nt) {
            const int row = m0 + wm + mt * 16 + q * 4;
            const int col = c0 + wn + nt * 16 + lm;
#pragma unroll
            for (int r = 0; r < 4; ++r)
                Yp[(size_t)(row + r) * ncols + col] = (_Float16)(acc[mt][nt][r] * AINV);
        }
    }
}

// ---------------- gate: MFMA weight apply; writes X2T (h-cols), zh, rbuf ----------------
// cat[b][k]: 0 = x_t (src), 1..32 = h (Hs), 33 = A@x (AXP), 34..65 = A@h (Y), 66..95 = 0.
__global__ __launch_bounds__(256) void gate_kernel(const float* __restrict__ src, int tcur,
                                                   const _Float16* __restrict__ Y,
                                                   const _Float16* __restrict__ AXP,
                                                   const _Float16* __restrict__ Wgt,
                                                   const float* __restrict__ bg,
                                                   const float* __restrict__ Hs,
                                                   _Float16* __restrict__ X2T,
                                                   _Float16* __restrict__ zh,
                                                   _Float16* __restrict__ rbuf) {
    __shared__ _Float16 catL[4][32][GPAD];
    const int t = threadIdx.x;
    const int n0 = blockIdx.x * 4;
    {
        const int pair = t >> 1, which = t & 1;
        const int nd = pair >> 5, b = pair & 31;
        const int n1 = n0 + nd;
        if (which == 0) {
            catL[nd][b][0] = (_Float16)src[((size_t)b * NT + tcur) * NNODE + n1];
            const float* hp = Hs + (size_t)n1 * 1024 + b * 32;
#pragma unroll
            for (int i = 0; i < 32; ++i) catL[nd][b][1 + i] = (_Float16)hp[i];
#pragma unroll
            for (int i = 66; i < KPAD; i += 2) *(unsigned*)&catL[nd][b][i] = 0u;
        } else {
            const _Float16* ax = AXP + (size_t)n1 * NCX + tcur * 32 + b;
            catL[nd][b][33] = (_Float16)((float)ax[0] + (float)ax[AXPS] +
                                         (float)ax[2 * AXPS] + (float)ax[3 * AXPS]);
            const _Float16* yp = Y + (size_t)n1 * NCOL + b * 32;
#pragma unroll
            for (int i = 0; i < 32; ++i) {
                const float sv = (float)yp[i] + (float)yp[Y1S + i] +
                                 (float)yp[2 * Y1S + i] + (float)yp[3 * Y1S + i];
                catL[nd][b][34 + i] = (_Float16)sv;
            }
        }
    }
    __syncthreads();
    const int w = t >> 6, lane = t & 63, lm = lane & 15, q = lane >> 4;
    const int n = n0 + w;
    const _Float16* Wn = Wgt + (size_t)n * 6144;
    floatx4 acc[2][4] = {};
#pragma unroll
    for (int kt = 0; kt < 3; ++kt) {
        half8 af[2], bf[4];
#pragma unroll
        for (int mt = 0; mt < 2; ++mt)
            af[mt] = *(const half8*)&catL[w][mt * 16 + lm][kt * 32 + q * 8];
#pragma unroll
        for (int nt = 0; nt < 4; ++nt)
            bf[nt] = *(const half8*)(Wn + (nt * 16 + lm) * KPAD + kt * 32 + q * 8);
#pragma unroll
        for (int mt = 0; mt < 2; ++mt)
#pragma unroll
            for (int nt = 0; nt < 4; ++nt)
                acc[mt][nt] = __builtin_amdgcn_mfma_f32_16x16x32_f16(
                    af[mt], bf[nt], acc[mt][nt], 0, 0, 0);
    }
#pragma unroll
    for (int nt = 0; nt < 4; ++nt) {
        const int o = nt * 16 + lm;
        const float bias = bg[n * 64 + o];
#pragma unroll
        for (int mt = 0; mt < 2; ++mt) {
#pragma unroll
            for (int r = 0; r < 4; ++r) {
                const int b = mt * 16 + q * 4 + r;
                const float s = 1.f / (1.f + expf(-(acc[mt][nt][r] + bias)));
                if (o < 32) {
                    const float hold = Hs[(size_t)n * 1024 + b * 32 + o];
                    const _Float16 zv = (_Float16)(s * hold);
                    zh[(size_t)n * 1024 + b * 32 + o] = zv;
                    X2T[(size_t)(b * 32 + o) * NNODE + n] = zv;
                } else {
                    rbuf[(size_t)n * 1024 + b * 32 + (o - 32)] = (_Float16)s;
                }
            }
        }
    }
}

// ---------------- update: MFMA weight apply; writes Hs (fp32) + XT (h-cols) ----------------
__global__ __launch_bounds__(256) void upd_kernel(const float* __restrict__ src, int tcur,
                                                  const _Float16* __restrict__ Y,
                                                  const _Float16* __restrict__ AXP,
                                                  const _Float16* __restrict__ Wut,
                                                  const float* __restrict__ bu,
                                                  const _Float16* __restrict__ zh,
                                                  const _Float16* __restrict__ rbuf,
                                                  float* __restrict__ Hs,
                                                  _Float16* __restrict__ XT) {
    __shared__ _Float16 catL[4][32][GPAD];
    const int t = threadIdx.x;
    const int n0 = blockIdx.x * 4;
    {
        const int pair = t >> 1, which = t & 1;
        const int nd = pair >> 5, b = pair & 31;
        const int n1 = n0 + nd;
        if (which == 0) {
            catL[nd][b][0] = (_Float16)src[((size_t)b * NT + tcur) * NNODE + n1];
            const _Float16* zp = zh + (size_t)n1 * 1024 + b * 32;
#pragma unroll
            for (int i = 0; i < 32; ++i) catL[nd][b][1 + i] = zp[i];
#pragma unroll
            for (int i = 66; i < KPAD; i += 2) *(unsigned*)&catL[nd][b][i] = 0u;
        } else {
            const _Float16* ax = AXP + (size_t)n1 * NCX + tcur * 32 + b;
            catL[nd][b][33] = (_Float16)((float)ax[0] + (float)ax[AXPS] +
                                         (float)ax[2 * AXPS] + (float)ax[3 * AXPS]);
            const _Float16* yp = Y + (size_t)n1 * NCOL + b * 32;
#pragma unroll
            for (int i = 0; i < 32; ++i) {
                const float sv = (float)yp[i] + (float)yp[Y1S + i] +
                                 (float)yp[2 * Y1S + i] + (float)yp[3 * Y1S + i];
                catL[nd][b][34 + i] = (_Float16)sv;
            }
        }
    }
    __syncthreads();
    const int w = t >> 6, lane = t & 63, lm = lane & 15, q = lane >> 4;
    const int n = n0 + w;
    const _Float16* Wn = Wut + (size_t)n * 3072;
    floatx4 acc[2][2] = {};
#pragma unroll
    for (int kt = 0; kt < 3; ++kt) {
        half8 af[2], bf[2];
#pragma unroll
        for (int mt = 0; mt < 2; ++mt)
            af[mt] = *(const half8*)&catL[w][mt * 16 + lm][kt * 32 + q * 8];
#pragma unroll
        for (int nt = 0; nt < 2; ++nt)
            bf[nt] = *(const half8*)(Wn + (nt * 16 + lm) * KPAD + kt * 32 + q * 8);
#pragma unroll
        for (int mt = 0; mt < 2; ++mt)
#pragma unroll
            for (int nt = 0; nt < 2; ++nt)
                acc[mt][nt] = __builtin_amdgcn_mfma_f32_16x16x32_f16(
                    af[mt], bf[nt], acc[mt][nt], 0, 0, 0);
    }
#pragma unroll
    for (int nt = 0; nt < 2; ++nt) {
        const int o = nt * 16 + lm;
        const float bias = bu[n * 32 + o];
#pragma unroll
        for (int mt = 0; mt < 2; ++mt) {
#pragma unroll
            for (int r = 0; r < 4; ++r) {
                const int b = mt * 16 + q * 4 + r;
                const float hc = tanhf(acc[mt][nt][r] + bias);
                const float rr = (float)rbuf[(size_t)n * 1024 + b * 32 + o];
                const size_t hidx = (size_t)n * 1024 + b * 32 + o;
                const float hnew = rr * Hs[hidx] + (1.f - rr) * hc;
                Hs[hidx] = hnew;
                XT[(size_t)(b * 32 + o) * NNODE + n] = (_Float16)hnew;
            }
        }
    }
}

// ---------------- out[b,0,n,t] = dot(h[b,n,:], convW[t,:]) + convb[t] ----------------
__global__ __launch_bounds__(256) void out_kernel(const float* __restrict__ Hs,
                                                  const float* __restrict__ cw,
                                                  const float* __restrict__ cb,
                                                  float* __restrict__ out) {
    __shared__ float h[NB * NH];
    __shared__ float cws[NT * NH];
    __shared__ float cbs[NT];
    const int n = blockIdx.x;
    const int t = threadIdx.x;
    for (int i = t; i < NT * NH; i += 256) cws[i] = cw[i];
    if (t < NT) cbs[t] = cb[t];
    for (int i = t; i < NB * NH; i += 256) h[i] = Hs[(size_t)n * 1024 + i];
    __syncthreads();
    for (int p = t; p < NB * NT; p += 256) {
        const int b = p / NT, tt = p % NT;
        float acc = cbs[tt];
#pragma unroll
        for (int j = 0; j < NH; ++j) acc += h[b * NH + j] * cws[tt * NH + j];
        out[(size_t)b * NNODE * NT + (size_t)n * NT + tt] = acc;
    }
}

extern "C" void kernel_launch(void* const* d_in, const int* in_sizes, int n_in,
                              void* d_out, int out_size, void* d_ws, size_t ws_size,
                              hipStream_t stream) {
    const float* src  = (const float*)d_in[0];
    const float* E    = (const float*)d_in[1];
    const float* gW   = (const float*)d_in[2];
    const float* gb   = (const float*)d_in[3];
    const float* uW   = (const float*)d_in[4];
    const float* ub   = (const float*)d_in[5];
    const float* cw   = (const float*)d_in[6];
    const float* cb   = (const float*)d_in[7];
    float* out = (float*)d_out;

    float* ws = (float*)d_ws;
    _Float16* Ah  = (_Float16*)(ws + OFF_AH);
    _Float16* Wgt = (_Float16*)(ws + OFF_WGT);
    _Float16* Wut = (_Float16*)(ws + OFF_WUT);
    float* bg  = ws + OFF_BG;
    float* bu  = ws + OFF_BU;
    _Float16* XT  = (_Float16*)(ws + OFF_XT);
    _Float16* X2T = (_Float16*)(ws + OFF_X2T);
    _Float16* SXT = (_Float16*)(ws + OFF_SXT);
    float* Hs  = ws + OFF_HS;
    _Float16* Y   = (_Float16*)(ws + OFF_Y);
    _Float16* AXP = (_Float16*)(ws + OFF_AXP);
    _Float16* rb  = (_Float16*)(ws + OFF_R);
    _Float16* zh  = (_Float16*)(ws + OFF_ZH);

    adj_kernel<<<NNODE, 256, 0, stream>>>(E, Ah);
    wg_kernel<<<NNODE, 256, 0, stream>>>(E, gW, Wgt);
    wu_kernel<<<NNODE, 256, 0, stream>>>(E, uW, Wut);
    bias_kernel<<<(NNODE * 96 + 255) / 256, 256, 0, stream>>>(E, gb, ub, bg, bu);
    setup_kernel<<<NNODE * NCOL / 256, 256, 0, stream>>>(src, XT, X2T, SXT, Hs);

    // A @ x_t for all 12 steps at once (384 cols, 3 col-tiles)
    mm_kernel<<<64 * 3, 256, 0, stream>>>(Ah, SXT, AXP, 3);

    for (int t = 0; t < NT; ++t) {
        mm_kernel<<<64 * 8, 256, 0, stream>>>(Ah, XT, Y, 8);
        gate_kernel<<<NNODE / 4, 256, 0, stream>>>(src, t, Y, AXP, Wgt, bg, Hs, X2T, zh, rb);
        mm_kernel<<<64 * 8, 256, 0, stream>>>(Ah, X2T, Y, 8);
        upd_kernel<<<NNODE / 4, 256, 0, stream>>>(src, t, Y, AXP, Wut, bu, zh, rb, Hs, XT);
    }
    out_kernel<<<NNODE, 256, 0, stream>>>(Hs, cw, cb, out);
}